// Round 6
// baseline (443.427 us; speedup 1.0000x reference)
//
#include <hip/hip_runtime.h>
#include <math.h>

#define NYg 1024
#define NXg 1024
#define W   1024
#define NSTEPS 64
#define NBLK 256
#define EN (NBLK * W)

typedef unsigned long long ull;

// ---- workspace layout ----
// dwords [0, 32768): ctrl. slotsf[s*256 + b] at dword 0 (65*256 = 16640 used).
//   per-block max-D for step s, plain system store, nonzero == published.
//   Seeded EPSf at s=0 by k_init (D(0)==EPS everywhere).
// byte 131072 onward: 8 packed halo arrays of EN x 64-bit (tag<<32 | f32 bits):
//   EZa0/EZa1 (z row r0+1, parity), EZb0/EZb1 (z row r0+3),
//   EDa0/EDa1 (D stag row r0),      EDb0/EDb1 (D stag row r0+3).
// Total = 131072 + 8*EN*8 = 16,908,288 B (same footprint as the proven R0 layout).
#define WS_CTRL_DW 32768
#define WS_TOTAL_U4 ((WS_CTRL_DW * 4 + 8 * EN * 8) / 16)

constexpr float DXf   = 50.0f;
constexpr float DYf   = 50.0f;
constexpr float TTOTf = 32.0f;
constexpr float DTMAXf= 0.5f;
constexpr float EPSf  = 1e-10f;
constexpr float TFREQ = 5.0f;
constexpr float LAPSE = 0.0065f;
constexpr float MELTF = 0.5f;
constexpr double RHOG = 910.0 * 9.81;
constexpr float  CDf  = (float)(1e-17 * RHOG * RHOG * RHOG);

// memory-side (coherence-point) accessors — bypass non-coherent per-XCD L2s
__device__ __forceinline__ float scloadf(const float* p) {
    return __hip_atomic_load(p, __ATOMIC_RELAXED, __HIP_MEMORY_SCOPE_SYSTEM);
}
__device__ __forceinline__ void scstoref(float* p, float v) {
    __hip_atomic_store(p, v, __ATOMIC_RELAXED, __HIP_MEMORY_SCOPE_SYSTEM);
}
__device__ __forceinline__ ull scload64(const ull* p) {
    return __hip_atomic_load(p, __ATOMIC_RELAXED, __HIP_MEMORY_SCOPE_SYSTEM);
}
__device__ __forceinline__ void scstore64(ull* p, ull v) {
    __hip_atomic_store(p, v, __ATOMIC_RELAXED, __HIP_MEMORY_SCOPE_SYSTEM);
}
__device__ __forceinline__ ull packtv(unsigned tag, float v) {
    return ((ull)tag << 32) | (ull)__float_as_uint(v);
}

// diffusivity on one staggered cell — expression verbatim (bit-exact)
__device__ __forceinline__ float dfunc(float h00, float h01, float h10, float h11,
                                       float z00, float z01, float z10, float z11)
{
    float havg = 0.25f * (h00 + h11 + h01 + h10);
    float sx = ((z01 - z00) + (z11 - z10)) * (0.5f / DXf);
    float sy = ((z10 - z00) + (z11 - z01)) * (0.5f / DYf);
    float sn = sqrtf(sx * sx + sy * sy + EPSf);
    float h2 = havg * havg;
    float h4 = h2 * h2;
    return CDf * (h4 * havg) * (sn * sn) + EPSf;
}

// ---------------- init: zero ctrl + halo tags, seed step-0 slots with EPS ----
__global__ __launch_bounds__(256) void k_init(uint4* __restrict__ ws)
{
    int idx = blockIdx.x * blockDim.x + threadIdx.x;
    int stride = gridDim.x * blockDim.x;
    const unsigned e = __float_as_uint(EPSf);
    for (int i = idx; i < (int)WS_TOTAL_U4; i += stride) {
        uint4 v = make_uint4(0u, 0u, 0u, 0u);
        if (i < NBLK / 4) v = make_uint4(e, e, e, e);   // slots[0..255] = EPS
        ws[i] = v;
    }
}

// ---------------- persistent kernel ----------------
// Conflict-free scalar b32 LDS (cross-lane slices only):
//   sZ[5][W] z rows r0..r0+4 ; sH[5][W] h rows ; sD[4][W] D stag rows r0..r0+3.
// Registers carry all own-column state incl. the 4 D-halo values.
// Sync protocol (this round):
//   - halo exports are PACKED (tag,value) 64-bit single stores: tag==s is the
//     ready flag, so there is NO export drain, NO nbf flag, NO second G barrier.
//   - A-phase: each thread polls its own <=6 packed words until tags==s.
//   - dt: per-block slot publish (value-as-flag, R4 scheme) unchanged.
__global__ __launch_bounds__(1024, 1) void k_run(
    ull* __restrict__ EZa0, ull* __restrict__ EZa1,
    ull* __restrict__ EZb0, ull* __restrict__ EZb1,
    ull* __restrict__ EDa0, ull* __restrict__ EDa1,
    ull* __restrict__ EDb0, ull* __restrict__ EDb1,
    const float* __restrict__ ztopo, const float* __restrict__ precip,
    const float* __restrict__ mask, const float* __restrict__ tma,
    const float* __restrict__ tmj, unsigned* __restrict__ ctrl,
    float* __restrict__ Hout)
{
    __shared__ float sZ[5][W];
    __shared__ float sH[5][W];
    __shared__ float sD[4][W];
    __shared__ float smax16[16];
    __shared__ float smax4[4];

    float* slotsf = (float*)ctrl;

    const int c   = threadIdx.x;          // column 0..1023
    const int b   = blockIdx.x;           // owns rows 4b..4b+3 (+1 redundant)
    const int r0  = b * 4;
    const int lane = c & 63, wid = c >> 6;
    const bool hasA = (b > 0), hasB = (b < NBLK - 1);
    const bool cL = (c >= 1), cR = (c <= NXg - 2);
    const int cm = (c == 0) ? 0 : c - 1;          // clamped (guard via iv)
    const int cp = (c == W - 1) ? W - 1 : c + 1;

    const float TMA = tma[0], TMJ = tmj[0];

    // register-carried own-column state
    float z_[7];                  // z rows r0-1 .. r0+5
    float h_[5];                  // h rows r0 .. r0+4
    float dreg[4];                // D stag rows r0..r0+3, col c
    float dtop, dtopL;            // D stag row r0-1, cols c / c-1
    float dbot, dbotL;            // D stag row r0+4, cols c / c-1
    float smbr[5], ztr[5];

    // ---- pre-loop: state(0) ----
    #pragma unroll
    for (int q = 0; q < 7; ++q) {
        int r = r0 - 1 + q;
        z_[q] = (r >= 0 && r < NYg) ? ztopo[r * W + c] : 0.0f;
    }
    #pragma unroll
    for (int rr = 0; rr < 5; ++rr) {
        int r = r0 + rr;
        h_[rr] = 0.0f;
        if (r < NYg) {
            float z = z_[rr + 1];
            ztr[rr] = z;
            float t_ma = TMA - LAPSE * z;
            float t_mj = TMJ - LAPSE * z;
            float acc  = (t_ma < 0.0f) ? precip[r * W + c] : 0.0f;
            float abl  = MELTF * fmaxf(t_mj, 0.0f);
            smbr[rr] = (acc - abl) * mask[r * W + c];
            sZ[rr][c] = z;
            sH[rr][c] = 0.0f;
        } else {
            ztr[rr] = 0.0f; smbr[rr] = 0.0f;
            sZ[rr][c] = 0.0f;
            sH[rr][c] = 0.0f;
        }
    }
    dtop = EPSf; dtopL = EPSf; dbot = EPSf; dbotL = EPSf;
    #pragma unroll
    for (int q = 0; q < 4; ++q) { dreg[q] = EPSf; sD[q][c] = EPSf; }
    __syncthreads();

    float t = 0.0f, tl = 0.0f;

    for (int s = 0; s < NSTEPS; ++s) {
        const ull* EZar = (s & 1) ? EZa1 : EZa0;   // z row r0+1, state s
        ull*       EZaw = (s & 1) ? EZa0 : EZa1;   // z row r0+1, state s+1
        const ull* EZbr = (s & 1) ? EZb1 : EZb0;   // z row r0+3, state s
        ull*       EZbw = (s & 1) ? EZb0 : EZb1;
        const ull* EDar = (s & 1) ? EDa1 : EDa0;   // D stag row r0, D(s)
        ull*       EDaw = (s & 1) ? EDa0 : EDa1;
        const ull* EDbr = (s & 1) ? EDb1 : EDb0;   // D stag row r0+3, D(s)
        ull*       EDbw = (s & 1) ? EDb0 : EDb1;

        // ---- A: per-thread tagged-halo poll+load (no barrier, no flags) ----
        if (s > 0) {
            const unsigned tg = (unsigned)s;
            const ull RD = ((ull)tg << 32);        // "ready" default, value 0
            ull vzt = RD, vdt = RD, vdtl = RD, vzb = RD, vdb = RD, vdbl = RD;
            const ull* pZt  = EZbr + (b - 1) * W + c;
            const ull* pDt  = EDbr + (b - 1) * W + c;
            const ull* pDtl = EDbr + (b - 1) * W + (c - 1);
            const ull* pZb  = EZar + (b + 1) * W + c;
            const ull* pDb  = EDar + (b + 1) * W + c;
            const ull* pDbl = EDar + (b + 1) * W + (c - 1);
            for (;;) {
                if (hasA) {
                    vzt = scload64(pZt);
                    if (cR) vdt  = scload64(pDt);
                    if (cL) vdtl = scload64(pDtl);
                }
                if (hasB) {
                    vzb = scload64(pZb);
                    if (cR) vdb  = scload64(pDb);
                    if (cL) vdbl = scload64(pDbl);
                }
                bool ok = ((unsigned)(vzt  >> 32) == tg) & ((unsigned)(vdt  >> 32) == tg)
                        & ((unsigned)(vdtl >> 32) == tg) & ((unsigned)(vzb  >> 32) == tg)
                        & ((unsigned)(vdb  >> 32) == tg) & ((unsigned)(vdbl >> 32) == tg);
                if (ok) break;
                __builtin_amdgcn_s_sleep(1);
            }
            if (hasA) z_[0] = __uint_as_float((unsigned)vzt);
            if (hasB) z_[6] = __uint_as_float((unsigned)vzb);
            if (hasA && cR) dtop  = __uint_as_float((unsigned)vdt);
            if (hasA && cL) dtopL = __uint_as_float((unsigned)vdtl);
            if (hasB && cR) dbot  = __uint_as_float((unsigned)vdb);
            if (hasB && cL) dbotL = __uint_as_float((unsigned)vdbl);
        }

        // ---- C1: dHdt (dt-independent). Shared qy interfaces (bit-exact) ----
        float dl[6], doa[6];
        dl[0] = dtopL;      doa[0] = dtop;
        dl[1] = sD[0][cm];  doa[1] = dreg[0];
        dl[2] = sD[1][cm];  doa[2] = dreg[1];
        dl[3] = sD[2][cm];  doa[3] = dreg[2];
        dl[4] = sD[3][cm];  doa[4] = dreg[3];
        dl[5] = dbotL;      doa[5] = dbot;

        float zl[5], zr[5];
        #pragma unroll
        for (int q = 0; q < 5; ++q) { zl[q] = sZ[q][cm]; zr[q] = sZ[q][cp]; }

        // vertical flux interface k: qyT(rr)=qy[rr], qyB(rr)=qy[rr+1]
        float qy[6];
        #pragma unroll
        for (int k = 0; k < 6; ++k)
            qy[k] = -0.5f * (dl[k] + doa[k]) * (z_[k + 1] - z_[k]) * (1.0f / DYf);

        float dh[5];
        bool  inter[5];
        #pragma unroll
        for (int rr = 0; rr < 5; ++rr) {
            int r = r0 + rr;
            bool iv = (r >= 1 && r <= NYg - 2 && cL && cR);
            float zc  = z_[rr + 1];
            float qxR = -0.5f * (doa[rr] + doa[rr + 1]) * (zr[rr] - zc) * (1.0f / DXf);
            float qxL = -0.5f * (dl[rr]  + dl[rr + 1])  * (zc - zl[rr]) * (1.0f / DXf);
            float d = -((qxR - qxL) * (1.0f / DXf) + (qy[rr + 1] - qy[rr]) * (1.0f / DYf));
            dh[rr] = iv ? d : 0.0f;
            inter[rr] = iv;
        }

        // ---- W: lanes 0..255 poll per-block slots (value==flag), reduce ----
        if (c < NBLK) {
            const float* sl = slotsf + s * NBLK + c;
            float v = scloadf(sl);
            while (__float_as_uint(v) == 0u) { __builtin_amdgcn_s_sleep(1); v = scloadf(sl); }
            #pragma unroll
            for (int off = 32; off >= 1; off >>= 1)
                v = fmaxf(v, __shfl_xor(v, off, 64));
            if (lane == 0) smax4[wid] = v;
        }
        __syncthreads();   // smax4 visible; also: C1 LDS reads done before C2 writes

        float mD = fmaxf(fmaxf(smax4[0], smax4[1]), fmaxf(smax4[2], smax4[3]));
        float dt = fminf(2500.0f / (2.7f * mD), DTMAXf);
        if (!(t < TTOTf)) dt = 0.0f;
        float nt  = t + dt;
        bool  upd = (nt - tl) >= TFREQ;

        // ---- C2+E: finalize h/z in regs, write b32 LDS, packed export, smb ----
        #pragma unroll
        for (int rr = 0; rr < 5; ++rr) {
            int r = r0 + rr;
            if (r < NYg) {
                float h, z;
                if (inter[rr]) { h = fmaxf(h_[rr] + dt * (dh[rr] + smbr[rr]), 0.0f);
                                 z = ztr[rr] + h; }
                else           { h = 0.0f; z = z_[rr + 1]; }
                h_[rr] = h; z_[rr + 1] = z;
                sZ[rr][c] = z;
                sH[rr][c] = h;
                if (rr == 1 && hasA) scstore64(EZaw + b * W + c, packtv((unsigned)(s + 1), z));
                if (rr == 3 && hasB) scstore64(EZbw + b * W + c, packtv((unsigned)(s + 1), z));
                if (upd) {
                    float t_ma = TMA - LAPSE * z;
                    float t_mj = TMJ - LAPSE * z;
                    float acc  = (t_ma < 0.0f) ? precip[r * W + c] : 0.0f;
                    float abl  = MELTF * fmaxf(t_mj, 0.0f);
                    smbr[rr] = (acc - abl) * mask[r * W + c];
                }
            } else {
                h_[rr] = 0.0f;
            }
        }
        __syncthreads();   // (z,h) writeback visible for G

        // ---- G: D(s+1); packed edge export; slot publish; ONE barrier ----
        if (s < NSTEPS - 1) {
            float m = 0.0f;
            float dv[4];
            #pragma unroll
            for (int rr = 0; rr < 4; ++rr) {
                int i = r0 + rr;
                float dd = 0.0f;
                if (i <= NYg - 2 && cR) {
                    dd = dfunc(h_[rr], sH[rr][c + 1],
                               h_[rr + 1], sH[rr + 1][c + 1],
                               z_[rr + 1], sZ[rr][c + 1],
                               z_[rr + 2], sZ[rr + 1][c + 1]);
                    m = fmaxf(m, dd);
                    if (rr == 0 && hasA) scstore64(EDaw + b * W + c, packtv((unsigned)(s + 1), dd));
                    if (rr == 3 && hasB) scstore64(EDbw + b * W + c, packtv((unsigned)(s + 1), dd));
                }
                dv[rr] = dd;
            }
            sD[0][c] = dv[0];
            sD[1][c] = dv[1];
            sD[2][c] = dv[2];
            sD[3][c] = dv[3];
            dreg[0] = dv[0]; dreg[1] = dv[1]; dreg[2] = dv[2]; dreg[3] = dv[3];
            #pragma unroll
            for (int off = 32; off >= 1; off >>= 1)
                m = fmaxf(m, __shfl_xor(m, off, 64));
            if (lane == 0) smax16[wid] = m;
            __syncthreads();                         // smax16 + sD visible
            if (c == 0) {
                #pragma unroll
                for (int q = 1; q < 16; ++q) m = fmaxf(m, smax16[q]);
                scstoref(slotsf + (s + 1) * NBLK + b, m);   // value==flag, no drain
            }
        }

        t = nt;
        if (upd) tl = nt;
    }

    // ---- final: H(64) own rows -> d_out ----
    #pragma unroll
    for (int rr = 0; rr < 4; ++rr)
        Hout[(r0 + rr) * W + c] = h_[rr];
}

extern "C" void kernel_launch(void* const* d_in, const int* in_sizes, int n_in,
                              void* d_out, int out_size, void* d_ws, size_t ws_size,
                              hipStream_t stream)
{
    const float* precip = (const float*)d_in[0];
    const float* tma    = (const float*)d_in[1];
    const float* tmj    = (const float*)d_in[2];
    const float* ztopo  = (const float*)d_in[3];
    const float* mask   = (const float*)d_in[4];

    unsigned* ctrl = (unsigned*)d_ws;
    ull* hp = (ull*)((char*)d_ws + WS_CTRL_DW * 4);
    ull* EZa0 = hp + 0 * EN; ull* EZa1 = hp + 1 * EN;
    ull* EZb0 = hp + 2 * EN; ull* EZb1 = hp + 3 * EN;
    ull* EDa0 = hp + 4 * EN; ull* EDa1 = hp + 5 * EN;
    ull* EDb0 = hp + 6 * EN; ull* EDb1 = hp + 7 * EN;

    k_init<<<dim3(2048), dim3(256), 0, stream>>>((uint4*)d_ws);

    k_run<<<dim3(256), dim3(1024), 0, stream>>>(EZa0, EZa1, EZb0, EZb1,
                                                EDa0, EDa1, EDb0, EDb1,
                                                ztopo, precip, mask, tma, tmj,
                                                ctrl, (float*)d_out);
}